// Round 12
// baseline (311.379 us; speedup 1.0000x reference)
//
#include <hip/hip_runtime.h>
#include <hip/hip_fp16.h>

// ---------------------------------------------------------------------------
// GCN 2-layer (PyG GCNConv) on MI355X — R12.
// agg1 is at its gather-line roofline (410MB lines / 61us = 6.7 TB/s); this
// round attacks the invisible ~236us in the build kernels:
//  * BSIZE 512->128: finalize 196 -> 782 blocks (was <=1 block/CU, 12.5% occ).
//  * finalize caches the bucket's edges in LDS (4608 x 8B): pass 2 reads LDS,
//    deleting the second 25.6MB latency-bound global pass.
//  * hist stored bucket-major (scan_bucket coalesced); histS chunk-major
//    (scatter coalesced) — the old layouts read 4B per 128B line.
// agg1/agg2/gemm identical to R11 (best: 297us).
// ---------------------------------------------------------------------------

#define BSHIFT 7
#define BSIZE 128            // nodes per bucket
#define MAXBKT 1024          // scan capacity (buckets and chunks <= 1024)
#define ECAP 4608            // finalize LDS edge cache (bucket mean 4096, +8 sigma)

typedef _Float16 f16x8 __attribute__((ext_vector_type(8)));
typedef float    f32x4 __attribute__((ext_vector_type(4)));

// ---------------- CSR build ----------------

// LDS histogram of col>>7 per 4096-edge chunk; write bucket-major.
__global__ __launch_bounds__(256) void k_hist(const int* __restrict__ col,
                                              int* __restrict__ hist,
                                              int E4, int nbl, int nbkt) {
    __shared__ int h[MAXBKT];
    int t = threadIdx.x, bl = blockIdx.x;
    for (int i = t; i < nbkt; i += 256) h[i] = 0;
    __syncthreads();
#pragma unroll
    for (int i = 0; i < 4; ++i) {
        int idx = bl * 1024 + i * 256 + t;
        if (idx < E4) {
            int4 c = ((const int4*)col)[idx];
            atomicAdd(&h[c.x >> BSHIFT], 1);
            atomicAdd(&h[c.y >> BSHIFT], 1);
            atomicAdd(&h[c.z >> BSHIFT], 1);
            atomicAdd(&h[c.w >> BSHIFT], 1);
        }
    }
    __syncthreads();
    for (int i = t; i < nbkt; i += 256) hist[(size_t)i * nbl + bl] = h[i];
}

// Block b: exclusive scan of hist[b][chunk] (coalesced); histS chunk-major.
__global__ __launch_bounds__(256) void k_scan_bucket(const int* __restrict__ hist,
                                                     int* __restrict__ histS,
                                                     int* __restrict__ tot,
                                                     int nbl, int nbkt) {
    __shared__ int A[2][MAXBKT];
    int b = blockIdx.x, t = threadIdx.x;
    for (int i = t; i < MAXBKT; i += 256)
        A[0][i] = (i < nbl) ? hist[(size_t)b * nbl + i] : 0;
    __syncthreads();
    int src = 0;
    for (int off = 1; off < MAXBKT; off <<= 1) {
        for (int i = t; i < MAXBKT; i += 256)
            A[1 - src][i] = A[src][i] + ((i >= off) ? A[src][i - off] : 0);
        src ^= 1;
        __syncthreads();
    }
    for (int i = t; i < nbl; i += 256)
        histS[(size_t)i * nbkt + b] = (i > 0) ? A[src][i - 1] : 0;
    if (t == 0) tot[b] = A[src][nbl - 1];
}

__global__ __launch_bounds__(256) void k_scan_tot(const int* __restrict__ tot,
                                                  int* __restrict__ base, int nbkt) {
    __shared__ int A[2][MAXBKT];
    int t = threadIdx.x;
    for (int i = t; i < MAXBKT; i += 256) A[0][i] = (i < nbkt) ? tot[i] : 0;
    __syncthreads();
    int src = 0;
    for (int off = 1; off < MAXBKT; off <<= 1) {
        for (int i = t; i < MAXBKT; i += 256)
            A[1 - src][i] = A[src][i] + ((i >= off) ? A[src][i - off] : 0);
        src ^= 1;
        __syncthreads();
    }
    for (int i = t; i < nbkt; i += 256) base[i] = (i > 0) ? A[src][i - 1] : 0;
    if (t == 0) base[nbkt] = A[src][nbkt - 1];
}

// Bucket-grouped scatter; LDS cursors (coalesced init); one 8B store per edge.
__global__ __launch_bounds__(256) void k_scatter(const int* __restrict__ ei,
                                                 const float* __restrict__ ea,
                                                 const int* __restrict__ histS,
                                                 const int* __restrict__ base,
                                                 int2* __restrict__ binned,
                                                 int E, int E4, int nbkt) {
    __shared__ int cur[MAXBKT];
    int t = threadIdx.x, bl = blockIdx.x;
    for (int i = t; i < nbkt; i += 256)
        cur[i] = base[i] + histS[(size_t)bl * nbkt + i];
    __syncthreads();
#pragma unroll
    for (int i = 0; i < 4; ++i) {
        int idx = bl * 1024 + i * 256 + t;
        if (idx < E4) {
            int4   r = ((const int4*)ei)[idx];
            int4   c = ((const int4*)(ei + E))[idx];
            float4 w = ((const float4*)ea)[idx];
            int p;
            p = atomicAdd(&cur[c.x >> BSHIFT], 1);
            binned[p] = make_int2(((c.x & (BSIZE - 1)) << 17) | r.x, __float_as_int(w.x));
            p = atomicAdd(&cur[c.y >> BSHIFT], 1);
            binned[p] = make_int2(((c.y & (BSIZE - 1)) << 17) | r.y, __float_as_int(w.y));
            p = atomicAdd(&cur[c.z >> BSHIFT], 1);
            binned[p] = make_int2(((c.z & (BSIZE - 1)) << 17) | r.z, __float_as_int(w.z));
            p = atomicAdd(&cur[c.w >> BSHIFT], 1);
            binned[p] = make_int2(((c.w & (BSIZE - 1)) << 17) | r.w, __float_as_int(w.w));
        }
    }
}

// One block per 128-node bucket. Pass 1 caches edges in LDS while counting;
// scan; pass 2 places from LDS. Emits offset, dinv, csr (hb<<17|row, 4B).
__global__ __launch_bounds__(256) void k_finalize(const int2* __restrict__ binned,
                                                  const int* __restrict__ base,
                                                  unsigned* __restrict__ csr,
                                                  int* __restrict__ offset,
                                                  float* __restrict__ dinv,
                                                  int N, int E) {
    __shared__ int2  ec[ECAP];
    __shared__ int   cnt[BSIZE];
    __shared__ float fsum[BSIZE];
    __shared__ int   inc[2][BSIZE];
    __shared__ int   cur[BSIZE];
    int b = blockIdx.x, t = threadIdx.x;
    int e0 = base[b], e1 = base[b + 1];
    for (int i = t; i < BSIZE; i += 256) { cnt[i] = 0; fsum[i] = 0.f; }
    __syncthreads();
    for (int e = e0 + t; e < e1; e += 256) {
        int2 ed = binned[e];
        int idx = e - e0;
        if (idx < ECAP) ec[idx] = ed;
        unsigned cl = ((unsigned)ed.x) >> 17;
        atomicAdd(&cnt[cl], 1);
        atomicAdd(&fsum[cl], __int_as_float(ed.y));
    }
    __syncthreads();
    for (int i = t; i < BSIZE; i += 256) inc[0][i] = cnt[i];
    __syncthreads();
    int src = 0;
    for (int off = 1; off < BSIZE; off <<= 1) {
        for (int i = t; i < BSIZE; i += 256)
            inc[1 - src][i] = inc[src][i] + ((i >= off) ? inc[src][i - off] : 0);
        src ^= 1;
        __syncthreads();
    }
    int nodeBase = b << BSHIFT;
    for (int i = t; i < BSIZE; i += 256) {
        int ex = (i > 0) ? inc[src][i - 1] : 0;
        cur[i] = e0 + ex;
        int node = nodeBase + i;
        if (node < N) {
            offset[node] = e0 + ex;
            dinv[node]   = rsqrtf(1.0f + fsum[i]);
        }
    }
    if (b == 0 && t == 0) offset[N] = E;
    __syncthreads();
    for (int e = e0 + t; e < e1; e += 256) {
        int idx = e - e0;
        int2 ed = (idx < ECAP) ? ec[idx] : binned[e];
        unsigned cl = ((unsigned)ed.x) >> 17;
        unsigned row = ((unsigned)ed.x) & 0x1FFFF;
        unsigned hb = (unsigned)__half_as_ushort(__float2half_rn(__int_as_float(ed.y))) & 0x7FFFu;
        int p = atomicAdd(&cur[cl], 1);
        csr[p] = (hb << 17) | row;
    }
}

// ---------------- dense compute (identical to R11) ----------------

__global__ __launch_bounds__(256) void k_gemm_mfma(const float* __restrict__ x,
                                                   const float* __restrict__ W1,
                                                   const float* __restrict__ dinv,
                                                   __half* __restrict__ hs, int n) {
    __shared__ _Float16 xh[64][136];
    __shared__ _Float16 wTh[64][136];
    int t = threadIdx.x;
    int nodeBase = blockIdx.x * 64;

    for (int i = t; i < 2048; i += 256) {
        int r = i >> 5, c4 = i & 31;
        int node = nodeBase + r;
        float4 v = make_float4(0.f, 0.f, 0.f, 0.f);
        if (node < n) v = ((const float4*)x)[node * 32 + c4];
        _Float16* dst = &xh[r][c4 * 4];
        dst[0] = (_Float16)v.x; dst[1] = (_Float16)v.y;
        dst[2] = (_Float16)v.z; dst[3] = (_Float16)v.w;
    }
    for (int i = t; i < 2048; i += 256) {
        int k = i >> 4, c4 = i & 15;
        float4 v = ((const float4*)W1)[k * 16 + c4];
        wTh[c4 * 4 + 0][k] = (_Float16)v.x;
        wTh[c4 * 4 + 1][k] = (_Float16)v.y;
        wTh[c4 * 4 + 2][k] = (_Float16)v.z;
        wTh[c4 * 4 + 3][k] = (_Float16)v.w;
    }
    __syncthreads();

    int w = t >> 6, lane = t & 63;
    int m = lane & 15, quad = lane >> 4;

    f32x4 acc[4] = {{0.f,0.f,0.f,0.f},{0.f,0.f,0.f,0.f},
                    {0.f,0.f,0.f,0.f},{0.f,0.f,0.f,0.f}};
#pragma unroll
    for (int ks = 0; ks < 128; ks += 32) {
        f16x8 a = *(const f16x8*)&xh[w * 16 + m][ks + quad * 8];
#pragma unroll
        for (int ct = 0; ct < 4; ++ct) {
            f16x8 bfr = *(const f16x8*)&wTh[ct * 16 + m][ks + quad * 8];
            acc[ct] = __builtin_amdgcn_mfma_f32_16x16x32_f16(a, bfr, acc[ct], 0, 0, 0);
        }
    }

#pragma unroll
    for (int reg = 0; reg < 4; ++reg) {
        int node = nodeBase + w * 16 + quad * 4 + reg;
        if (node < n) {
            float dv = dinv[node];
#pragma unroll
            for (int ct = 0; ct < 4; ++ct) {
                float v = acc[ct][reg] * dv;
                hs[(size_t)node * 64 + ct * 16 + m] = __float2half_rn(v);
            }
        }
    }
}

__global__ __launch_bounds__(256) void k_agg1(const __half* __restrict__ hs,
                                              const int* __restrict__ offset,
                                              const unsigned* __restrict__ csr,
                                              const float* __restrict__ dinv,
                                              const float* __restrict__ b1,
                                              const float* __restrict__ W2,
                                              float* __restrict__ h2s, int n) {
    int wid  = (int)((blockIdx.x * blockDim.x + threadIdx.x) >> 6);
    int lane = threadIdx.x & 63;
    if (wid >= n) return;
    int off0 = offset[wid], off1 = offset[wid + 1];
    int g = lane >> 3, s = lane & 7;
    const f16x8* H = (const f16x8*)hs;

    float acc[8] = {0.f, 0.f, 0.f, 0.f, 0.f, 0.f, 0.f, 0.f};

    {
        f16x8 v = H[(size_t)wid * 8 + s];
        if (g == 0) {
#pragma unroll
            for (int k = 0; k < 8; ++k) acc[k] += (float)v[k];
        }
    }

    for (int j = off0; j < off1; j += 32) {
        int   i0 = j + g,      i1 = j + 8 + g,  i2 = j + 16 + g, i3 = j + 24 + g;
        bool  k0 = i0 < off1,  k1 = i1 < off1,  k2 = i2 < off1,  k3 = i3 < off1;
        unsigned eA = csr[k0 ? i0 : off1 - 1];
        unsigned eB = csr[k1 ? i1 : off1 - 1];
        unsigned eC = csr[k2 ? i2 : off1 - 1];
        unsigned eD = csr[k3 ? i3 : off1 - 1];
        f16x8 vA = H[(size_t)(eA & 0x1FFFF) * 8 + s];
        f16x8 vB = H[(size_t)(eB & 0x1FFFF) * 8 + s];
        f16x8 vC = H[(size_t)(eC & 0x1FFFF) * 8 + s];
        f16x8 vD = H[(size_t)(eD & 0x1FFFF) * 8 + s];
        float wA = k0 ? (float)__ushort_as_half((unsigned short)(eA >> 17)) : 0.f;
        float wB = k1 ? (float)__ushort_as_half((unsigned short)(eB >> 17)) : 0.f;
        float wC = k2 ? (float)__ushort_as_half((unsigned short)(eC >> 17)) : 0.f;
        float wD = k3 ? (float)__ushort_as_half((unsigned short)(eD >> 17)) : 0.f;
#pragma unroll
        for (int k = 0; k < 8; ++k) {
            acc[k] += wA * (float)vA[k];
            acc[k] += wB * (float)vB[k];
            acc[k] += wC * (float)vC[k];
            acc[k] += wD * (float)vD[k];
        }
    }

#pragma unroll
    for (int k = 0; k < 8; ++k) {
        float tv = acc[k];
        tv += __shfl_xor(tv, 8);
        tv += __shfl_xor(tv, 16);
        tv += __shfl_xor(tv, 32);
        acc[k] = tv;
    }

    float di = dinv[wid];
    float4 bA = ((const float4*)b1)[s * 2], bB = ((const float4*)b1)[s * 2 + 1];
    float4 wA = ((const float4*)W2)[s * 2], wB = ((const float4*)W2)[s * 2 + 1];
    float p = 0.f;
    p += fmaxf(di * acc[0] + bA.x, 0.f) * wA.x;
    p += fmaxf(di * acc[1] + bA.y, 0.f) * wA.y;
    p += fmaxf(di * acc[2] + bA.z, 0.f) * wA.z;
    p += fmaxf(di * acc[3] + bA.w, 0.f) * wA.w;
    p += fmaxf(di * acc[4] + bB.x, 0.f) * wB.x;
    p += fmaxf(di * acc[5] + bB.y, 0.f) * wB.y;
    p += fmaxf(di * acc[6] + bB.z, 0.f) * wB.z;
    p += fmaxf(di * acc[7] + bB.w, 0.f) * wB.w;
    p += __shfl_xor(p, 1);
    p += __shfl_xor(p, 2);
    p += __shfl_xor(p, 4);
    if (lane == 0) h2s[wid] = di * p;
}

__global__ __launch_bounds__(256) void k_agg2(const float* __restrict__ h2s,
                                              const int* __restrict__ offset,
                                              const unsigned* __restrict__ csr,
                                              const float* __restrict__ dinv,
                                              const float* __restrict__ b2,
                                              float* __restrict__ out, int n) {
    int wid = __builtin_amdgcn_readfirstlane((int)((blockIdx.x * blockDim.x + threadIdx.x) >> 6));
    int lane = threadIdx.x & 63;
    if (wid >= n) return;
    int off0 = __builtin_amdgcn_readfirstlane(offset[wid]);
    int off1 = __builtin_amdgcn_readfirstlane(offset[wid + 1]);
    float di = dinv[wid];
    float p = 0.f;
    for (int e = off0 + lane; e < off1; e += 64) {
        unsigned ed = csr[e];
        p += (float)__ushort_as_half((unsigned short)(ed >> 17)) * h2s[ed & 0x1FFFF];
    }
#pragma unroll
    for (int s = 32; s > 0; s >>= 1) p += __shfl_xor(p, s);
    if (lane == 0) out[wid] = di * (p + h2s[wid]) + b2[0];
}

extern "C" void kernel_launch(void* const* d_in, const int* in_sizes, int n_in,
                              void* d_out, int out_size, void* d_ws, size_t ws_size,
                              hipStream_t stream) {
    const float* x  = (const float*)d_in[0];
    const int*   ei = (const int*)  d_in[1];
    const float* ea = (const float*)d_in[2];
    const float* W1 = (const float*)d_in[3];
    const float* b1 = (const float*)d_in[4];
    const float* W2 = (const float*)d_in[5];
    const float* b2 = (const float*)d_in[6];
    float* out = (float*)d_out;

    const int N  = in_sizes[0] / 128;   // 100000 (requires N <= 131072)
    const int E  = in_sizes[2];         // 3200000
    const int E4 = E / 4;
    const int nbl  = (E4 + 1023) / 1024;          // chunks (782)
    const int nbkt = (N + BSIZE - 1) / BSIZE;     // buckets (782)

    char* p = (char*)d_ws;
    auto alloc = [&](size_t bytes) -> void* {
        void* r = (void*)p;
        p += (bytes + 255) & ~(size_t)255;
        return r;
    };
    int*       hist   = (int*)      alloc((size_t)nbkt * nbl * 4);
    int*       histS  = (int*)      alloc((size_t)nbl * nbkt * 4);
    int*       tot    = (int*)      alloc((size_t)nbkt * 4);
    int*       base   = (int*)      alloc((size_t)(nbkt + 1) * 4);
    int2*      binned = (int2*)     alloc((size_t)E * 8);
    unsigned*  csr    = (unsigned*) alloc((size_t)E * 4);
    int*       offset = (int*)      alloc((size_t)(N + 1) * 4);
    float*     dinv   = (float*)    alloc((size_t)N * 4);
    __half*    hs     = (__half*)   alloc((size_t)N * 64 * 2);
    float*     h2s    = (float*)    alloc((size_t)N * 4);

    const int nb_gemm = (N + 63) / 64;
    const int nb_wave = (N * 64 + 255) / 256;   // one 64-wide wave per node

    k_hist<<<nbl, 256, 0, stream>>>(ei + E, hist, E4, nbl, nbkt);
    k_scan_bucket<<<nbkt, 256, 0, stream>>>(hist, histS, tot, nbl, nbkt);
    k_scan_tot<<<1, 256, 0, stream>>>(tot, base, nbkt);
    k_scatter<<<nbl, 256, 0, stream>>>(ei, ea, histS, base, binned, E, E4, nbkt);
    k_finalize<<<nbkt, 256, 0, stream>>>(binned, base, csr, offset, dinv, N, E);
    k_gemm_mfma<<<nb_gemm, 256, 0, stream>>>(x, W1, dinv, hs, N);
    k_agg1<<<nb_wave, 256, 0, stream>>>(hs, offset, csr, dinv, b1, W2, h2s, N);
    k_agg2<<<nb_wave, 256, 0, stream>>>(h2s, offset, csr, dinv, b2, out, N);
}

// Round 13
// 296.855 us; speedup vs baseline: 1.0489x; 1.0489x over previous
//
#include <hip/hip_runtime.h>
#include <hip/hip_fp16.h>

// ---------------------------------------------------------------------------
// GCN 2-layer (PyG GCNConv) on MI355X — R13.
// R12 (BSIZE-128 rebuild) regressed -14us: moved uncoalescing to the write
// side + worse scatter locality. REVERTED to R11 (best: 297us). Delta:
//  * k_finalize: block 256 -> 1024 threads. Was 196 blocks x 4 waves =
//    <=1 block/CU / 4 waves/CU for two latency-bound 25.6MB passes. Now
//    16 waves/block, 2 blocks/CU -> ~8x loads in flight per CU.
//  * k_scan_bucket: 1024 threads, one element/thread (halves load chain).
// Everything else byte-identical to R11.
// ---------------------------------------------------------------------------

#define BSHIFT 9
#define BSIZE 512            // nodes per bucket
#define NBUCKET 256          // max buckets (requires N <= 131072)

typedef _Float16 f16x8 __attribute__((ext_vector_type(8)));
typedef float    f32x4 __attribute__((ext_vector_type(4)));

// ---------------- CSR build ----------------

__global__ __launch_bounds__(256) void k_hist(const int* __restrict__ col,
                                              int* __restrict__ hist, int E4) {
    __shared__ int h[NBUCKET];
    int t = threadIdx.x, bl = blockIdx.x;
    h[t] = 0;
    __syncthreads();
#pragma unroll
    for (int i = 0; i < 4; ++i) {
        int idx = bl * 1024 + i * 256 + t;
        if (idx < E4) {
            int4 c = ((const int4*)col)[idx];
            atomicAdd(&h[c.x >> BSHIFT], 1);
            atomicAdd(&h[c.y >> BSHIFT], 1);
            atomicAdd(&h[c.z >> BSHIFT], 1);
            atomicAdd(&h[c.w >> BSHIFT], 1);
        }
    }
    __syncthreads();
    hist[bl * NBUCKET + t] = h[t];
}

// Block b: exclusive scan of hist[chunk][b] across chunks; 1 elem/thread.
__global__ __launch_bounds__(1024) void k_scan_bucket(const int* __restrict__ hist,
                                                      int* __restrict__ histS,
                                                      int* __restrict__ tot, int nbl) {
    __shared__ int A[2][1024];
    int b = blockIdx.x, t = threadIdx.x;
    A[0][t] = (t < nbl) ? hist[t * NBUCKET + b] : 0;
    __syncthreads();
    int src = 0;
    for (int off = 1; off < 1024; off <<= 1) {
        A[1 - src][t] = A[src][t] + ((t >= off) ? A[src][t - off] : 0);
        src ^= 1;
        __syncthreads();
    }
    if (t < nbl) histS[b * nbl + t] = (t > 0) ? A[src][t - 1] : 0;
    if (t == 0) tot[b] = A[src][nbl - 1];
}

__global__ __launch_bounds__(256) void k_scan_tot(const int* __restrict__ tot,
                                                  int* __restrict__ base) {
    __shared__ int A[2][NBUCKET];
    int t = threadIdx.x;
    A[0][t] = tot[t];
    __syncthreads();
    int src = 0;
    for (int off = 1; off < NBUCKET; off <<= 1) {
        A[1 - src][t] = A[src][t] + ((t >= off) ? A[src][t - off] : 0);
        src ^= 1;
        __syncthreads();
    }
    base[t] = (t > 0) ? A[src][t - 1] : 0;
    if (t == 255) base[NBUCKET] = A[src][255];
}

__global__ __launch_bounds__(256) void k_scatter(const int* __restrict__ ei,
                                                 const float* __restrict__ ea,
                                                 const int* __restrict__ histS,
                                                 const int* __restrict__ base,
                                                 int2* __restrict__ binned,
                                                 int E, int E4, int nbl) {
    __shared__ int cur[NBUCKET];
    int t = threadIdx.x, bl = blockIdx.x;
    cur[t] = base[t] + histS[t * nbl + bl];
    __syncthreads();
#pragma unroll
    for (int i = 0; i < 4; ++i) {
        int idx = bl * 1024 + i * 256 + t;
        if (idx < E4) {
            int4   r = ((const int4*)ei)[idx];
            int4   c = ((const int4*)(ei + E))[idx];
            float4 w = ((const float4*)ea)[idx];
            int p;
            p = atomicAdd(&cur[c.x >> BSHIFT], 1);
            binned[p] = make_int2(((c.x & (BSIZE - 1)) << 17) | r.x, __float_as_int(w.x));
            p = atomicAdd(&cur[c.y >> BSHIFT], 1);
            binned[p] = make_int2(((c.y & (BSIZE - 1)) << 17) | r.y, __float_as_int(w.y));
            p = atomicAdd(&cur[c.z >> BSHIFT], 1);
            binned[p] = make_int2(((c.z & (BSIZE - 1)) << 17) | r.z, __float_as_int(w.z));
            p = atomicAdd(&cur[c.w >> BSHIFT], 1);
            binned[p] = make_int2(((c.w & (BSIZE - 1)) << 17) | r.w, __float_as_int(w.w));
        }
    }
}

// One block (1024 threads, 16 waves) per 512-node bucket: count + ew-sum +
// scan in LDS; emit offset, dinv, csr[p] = f16bits(ew)[14:0]<<17 | row.
__global__ __launch_bounds__(1024) void k_finalize(const int2* __restrict__ binned,
                                                   const int* __restrict__ base,
                                                   unsigned* __restrict__ csr,
                                                   int* __restrict__ offset,
                                                   float* __restrict__ dinv,
                                                   int N, int E) {
    __shared__ int   cnt[BSIZE];
    __shared__ float fsum[BSIZE];
    __shared__ int   inc[2][BSIZE];
    __shared__ int   cur[BSIZE];
    int b = blockIdx.x, t = threadIdx.x;
    int e0 = base[b], e1 = base[b + 1];
    for (int i = t; i < BSIZE; i += 1024) { cnt[i] = 0; fsum[i] = 0.f; }
    __syncthreads();
    for (int e = e0 + t; e < e1; e += 1024) {
        int2 ed = binned[e];
        unsigned cl = ((unsigned)ed.x) >> 17;
        atomicAdd(&cnt[cl], 1);
        atomicAdd(&fsum[cl], __int_as_float(ed.y));
    }
    __syncthreads();
    for (int i = t; i < BSIZE; i += 1024) inc[0][i] = cnt[i];
    __syncthreads();
    int src = 0;
    for (int off = 1; off < BSIZE; off <<= 1) {
        for (int i = t; i < BSIZE; i += 1024)
            inc[1 - src][i] = inc[src][i] + ((i >= off) ? inc[src][i - off] : 0);
        src ^= 1;
        __syncthreads();
    }
    int nodeBase = b << BSHIFT;
    for (int i = t; i < BSIZE; i += 1024) {
        int ex = (i > 0) ? inc[src][i - 1] : 0;
        cur[i] = e0 + ex;
        int node = nodeBase + i;
        if (node < N) {
            offset[node] = e0 + ex;
            dinv[node]   = rsqrtf(1.0f + fsum[i]);
        }
    }
    if (b == 0 && t == 0) offset[N] = E;
    __syncthreads();
    for (int e = e0 + t; e < e1; e += 1024) {
        int2 ed = binned[e];
        unsigned cl = ((unsigned)ed.x) >> 17;
        unsigned row = ((unsigned)ed.x) & 0x1FFFF;
        unsigned hb = (unsigned)__half_as_ushort(__float2half_rn(__int_as_float(ed.y))) & 0x7FFFu;
        int p = atomicAdd(&cur[cl], 1);
        csr[p] = (hb << 17) | row;
    }
}

// ---------------- dense compute (identical to R11) ----------------

__global__ __launch_bounds__(256) void k_gemm_mfma(const float* __restrict__ x,
                                                   const float* __restrict__ W1,
                                                   const float* __restrict__ dinv,
                                                   __half* __restrict__ hs, int n) {
    __shared__ _Float16 xh[64][136];
    __shared__ _Float16 wTh[64][136];
    int t = threadIdx.x;
    int nodeBase = blockIdx.x * 64;

    for (int i = t; i < 2048; i += 256) {
        int r = i >> 5, c4 = i & 31;
        int node = nodeBase + r;
        float4 v = make_float4(0.f, 0.f, 0.f, 0.f);
        if (node < n) v = ((const float4*)x)[node * 32 + c4];
        _Float16* dst = &xh[r][c4 * 4];
        dst[0] = (_Float16)v.x; dst[1] = (_Float16)v.y;
        dst[2] = (_Float16)v.z; dst[3] = (_Float16)v.w;
    }
    for (int i = t; i < 2048; i += 256) {
        int k = i >> 4, c4 = i & 15;
        float4 v = ((const float4*)W1)[k * 16 + c4];
        wTh[c4 * 4 + 0][k] = (_Float16)v.x;
        wTh[c4 * 4 + 1][k] = (_Float16)v.y;
        wTh[c4 * 4 + 2][k] = (_Float16)v.z;
        wTh[c4 * 4 + 3][k] = (_Float16)v.w;
    }
    __syncthreads();

    int w = t >> 6, lane = t & 63;
    int m = lane & 15, quad = lane >> 4;

    f32x4 acc[4] = {{0.f,0.f,0.f,0.f},{0.f,0.f,0.f,0.f},
                    {0.f,0.f,0.f,0.f},{0.f,0.f,0.f,0.f}};
#pragma unroll
    for (int ks = 0; ks < 128; ks += 32) {
        f16x8 a = *(const f16x8*)&xh[w * 16 + m][ks + quad * 8];
#pragma unroll
        for (int ct = 0; ct < 4; ++ct) {
            f16x8 bfr = *(const f16x8*)&wTh[ct * 16 + m][ks + quad * 8];
            acc[ct] = __builtin_amdgcn_mfma_f32_16x16x32_f16(a, bfr, acc[ct], 0, 0, 0);
        }
    }

#pragma unroll
    for (int reg = 0; reg < 4; ++reg) {
        int node = nodeBase + w * 16 + quad * 4 + reg;
        if (node < n) {
            float dv = dinv[node];
#pragma unroll
            for (int ct = 0; ct < 4; ++ct) {
                float v = acc[ct][reg] * dv;
                hs[(size_t)node * 64 + ct * 16 + m] = __float2half_rn(v);
            }
        }
    }
}

__global__ __launch_bounds__(256) void k_agg1(const __half* __restrict__ hs,
                                              const int* __restrict__ offset,
                                              const unsigned* __restrict__ csr,
                                              const float* __restrict__ dinv,
                                              const float* __restrict__ b1,
                                              const float* __restrict__ W2,
                                              float* __restrict__ h2s, int n) {
    int wid  = (int)((blockIdx.x * blockDim.x + threadIdx.x) >> 6);
    int lane = threadIdx.x & 63;
    if (wid >= n) return;
    int off0 = offset[wid], off1 = offset[wid + 1];
    int g = lane >> 3, s = lane & 7;
    const f16x8* H = (const f16x8*)hs;

    float acc[8] = {0.f, 0.f, 0.f, 0.f, 0.f, 0.f, 0.f, 0.f};

    {
        f16x8 v = H[(size_t)wid * 8 + s];
        if (g == 0) {
#pragma unroll
            for (int k = 0; k < 8; ++k) acc[k] += (float)v[k];
        }
    }

    for (int j = off0; j < off1; j += 32) {
        int   i0 = j + g,      i1 = j + 8 + g,  i2 = j + 16 + g, i3 = j + 24 + g;
        bool  k0 = i0 < off1,  k1 = i1 < off1,  k2 = i2 < off1,  k3 = i3 < off1;
        unsigned eA = csr[k0 ? i0 : off1 - 1];
        unsigned eB = csr[k1 ? i1 : off1 - 1];
        unsigned eC = csr[k2 ? i2 : off1 - 1];
        unsigned eD = csr[k3 ? i3 : off1 - 1];
        f16x8 vA = H[(size_t)(eA & 0x1FFFF) * 8 + s];
        f16x8 vB = H[(size_t)(eB & 0x1FFFF) * 8 + s];
        f16x8 vC = H[(size_t)(eC & 0x1FFFF) * 8 + s];
        f16x8 vD = H[(size_t)(eD & 0x1FFFF) * 8 + s];
        float wA = k0 ? (float)__ushort_as_half((unsigned short)(eA >> 17)) : 0.f;
        float wB = k1 ? (float)__ushort_as_half((unsigned short)(eB >> 17)) : 0.f;
        float wC = k2 ? (float)__ushort_as_half((unsigned short)(eC >> 17)) : 0.f;
        float wD = k3 ? (float)__ushort_as_half((unsigned short)(eD >> 17)) : 0.f;
#pragma unroll
        for (int k = 0; k < 8; ++k) {
            acc[k] += wA * (float)vA[k];
            acc[k] += wB * (float)vB[k];
            acc[k] += wC * (float)vC[k];
            acc[k] += wD * (float)vD[k];
        }
    }

#pragma unroll
    for (int k = 0; k < 8; ++k) {
        float tv = acc[k];
        tv += __shfl_xor(tv, 8);
        tv += __shfl_xor(tv, 16);
        tv += __shfl_xor(tv, 32);
        acc[k] = tv;
    }

    float di = dinv[wid];
    float4 bA = ((const float4*)b1)[s * 2], bB = ((const float4*)b1)[s * 2 + 1];
    float4 wA = ((const float4*)W2)[s * 2], wB = ((const float4*)W2)[s * 2 + 1];
    float p = 0.f;
    p += fmaxf(di * acc[0] + bA.x, 0.f) * wA.x;
    p += fmaxf(di * acc[1] + bA.y, 0.f) * wA.y;
    p += fmaxf(di * acc[2] + bA.z, 0.f) * wA.z;
    p += fmaxf(di * acc[3] + bA.w, 0.f) * wA.w;
    p += fmaxf(di * acc[4] + bB.x, 0.f) * wB.x;
    p += fmaxf(di * acc[5] + bB.y, 0.f) * wB.y;
    p += fmaxf(di * acc[6] + bB.z, 0.f) * wB.z;
    p += fmaxf(di * acc[7] + bB.w, 0.f) * wB.w;
    p += __shfl_xor(p, 1);
    p += __shfl_xor(p, 2);
    p += __shfl_xor(p, 4);
    if (lane == 0) h2s[wid] = di * p;
}

__global__ __launch_bounds__(256) void k_agg2(const float* __restrict__ h2s,
                                              const int* __restrict__ offset,
                                              const unsigned* __restrict__ csr,
                                              const float* __restrict__ dinv,
                                              const float* __restrict__ b2,
                                              float* __restrict__ out, int n) {
    int wid = __builtin_amdgcn_readfirstlane((int)((blockIdx.x * blockDim.x + threadIdx.x) >> 6));
    int lane = threadIdx.x & 63;
    if (wid >= n) return;
    int off0 = __builtin_amdgcn_readfirstlane(offset[wid]);
    int off1 = __builtin_amdgcn_readfirstlane(offset[wid + 1]);
    float di = dinv[wid];
    float p = 0.f;
    for (int e = off0 + lane; e < off1; e += 64) {
        unsigned ed = csr[e];
        p += (float)__ushort_as_half((unsigned short)(ed >> 17)) * h2s[ed & 0x1FFFF];
    }
#pragma unroll
    for (int s = 32; s > 0; s >>= 1) p += __shfl_xor(p, s);
    if (lane == 0) out[wid] = di * (p + h2s[wid]) + b2[0];
}

extern "C" void kernel_launch(void* const* d_in, const int* in_sizes, int n_in,
                              void* d_out, int out_size, void* d_ws, size_t ws_size,
                              hipStream_t stream) {
    const float* x  = (const float*)d_in[0];
    const int*   ei = (const int*)  d_in[1];
    const float* ea = (const float*)d_in[2];
    const float* W1 = (const float*)d_in[3];
    const float* b1 = (const float*)d_in[4];
    const float* W2 = (const float*)d_in[5];
    const float* b2 = (const float*)d_in[6];
    float* out = (float*)d_out;

    const int N  = in_sizes[0] / 128;   // 100000 (must be <= 131072)
    const int E  = in_sizes[2];         // 3200000
    const int E4 = E / 4;
    const int nbl  = (E4 + 1023) / 1024;        // partition chunks (<=1024)
    const int nbkt = (N + BSIZE - 1) / BSIZE;   // active buckets (196)

    char* p = (char*)d_ws;
    auto alloc = [&](size_t bytes) -> void* {
        void* r = (void*)p;
        p += (bytes + 255) & ~(size_t)255;
        return r;
    };
    int*       hist   = (int*)      alloc((size_t)nbl * NBUCKET * 4);
    int*       histS  = (int*)      alloc((size_t)NBUCKET * nbl * 4);
    int*       tot    = (int*)      alloc((size_t)NBUCKET * 4);
    int*       base   = (int*)      alloc((size_t)(NBUCKET + 1) * 4);
    int2*      binned = (int2*)     alloc((size_t)E * 8);
    unsigned*  csr    = (unsigned*) alloc((size_t)E * 4);
    int*       offset = (int*)      alloc((size_t)(N + 1) * 4);
    float*     dinv   = (float*)    alloc((size_t)N * 4);
    __half*    hs     = (__half*)   alloc((size_t)N * 64 * 2);
    float*     h2s    = (float*)    alloc((size_t)N * 4);

    const int nb_gemm = (N + 63) / 64;
    const int nb_wave = (N * 64 + 255) / 256;   // one 64-wide wave per node

    k_hist<<<nbl, 256, 0, stream>>>(ei + E, hist, E4);
    k_scan_bucket<<<NBUCKET, 1024, 0, stream>>>(hist, histS, tot, nbl);
    k_scan_tot<<<1, 256, 0, stream>>>(tot, base);
    k_scatter<<<nbl, 256, 0, stream>>>(ei, ea, histS, base, binned, E, E4, nbl);
    k_finalize<<<nbkt, 1024, 0, stream>>>(binned, base, csr, offset, dinv, N, E);
    k_gemm_mfma<<<nb_gemm, 256, 0, stream>>>(x, W1, dinv, hs, N);
    k_agg1<<<nb_wave, 256, 0, stream>>>(hs, offset, csr, dinv, b1, W2, h2s, N);
    k_agg2<<<nb_wave, 256, 0, stream>>>(h2s, offset, csr, dinv, b2, out, N);
}

// Round 14
// 290.536 us; speedup vs baseline: 1.0717x; 1.0217x over previous
//
#include <hip/hip_runtime.h>
#include <hip/hip_fp16.h>

// ---------------------------------------------------------------------------
// GCN 2-layer (PyG GCNConv) on MI355X — R14.
// R13 learned: finalize was NOT the hidden cost (1024-thr neutral). New
// suspect: k_scatter's partial-line RFO amplification — 4096-edge chunks
// give 16 edges = 1 partial 128B line per (chunk,bucket) run.
// Delta vs R13 (one change): chunk 4096 -> 16384 edges (hist+scatter 1024
// threads, nbl 782 -> 196). Bucket runs become 512B = 4 full lines ->
// scatter write amplification ~2.0 -> ~1.25. Scans shrink 4x.
// agg1/agg2/gemm/finalize byte-identical to R13 (best: 296.9us).
// ---------------------------------------------------------------------------

#define BSHIFT 9
#define BSIZE 512            // nodes per bucket
#define NBUCKET 256          // max buckets (requires N <= 131072)

typedef _Float16 f16x8 __attribute__((ext_vector_type(8)));
typedef float    f32x4 __attribute__((ext_vector_type(4)));

// ---------------- CSR build ----------------

// 16384 edges per chunk, 1024 threads, 4 int4 per thread.
__global__ __launch_bounds__(1024) void k_hist(const int* __restrict__ col,
                                               int* __restrict__ hist, int E4) {
    __shared__ int h[NBUCKET];
    int t = threadIdx.x, bl = blockIdx.x;
    if (t < NBUCKET) h[t] = 0;
    __syncthreads();
#pragma unroll
    for (int i = 0; i < 4; ++i) {
        int idx = bl * 4096 + i * 1024 + t;
        if (idx < E4) {
            int4 c = ((const int4*)col)[idx];
            atomicAdd(&h[c.x >> BSHIFT], 1);
            atomicAdd(&h[c.y >> BSHIFT], 1);
            atomicAdd(&h[c.z >> BSHIFT], 1);
            atomicAdd(&h[c.w >> BSHIFT], 1);
        }
    }
    __syncthreads();
    if (t < NBUCKET) hist[bl * NBUCKET + t] = h[t];
}

// Block b: exclusive scan of hist[chunk][b] across chunks (nbl <= 256).
__global__ __launch_bounds__(256) void k_scan_bucket(const int* __restrict__ hist,
                                                     int* __restrict__ histS,
                                                     int* __restrict__ tot, int nbl) {
    __shared__ int A[2][256];
    int b = blockIdx.x, t = threadIdx.x;
    A[0][t] = (t < nbl) ? hist[t * NBUCKET + b] : 0;
    __syncthreads();
    int src = 0;
    for (int off = 1; off < 256; off <<= 1) {
        A[1 - src][t] = A[src][t] + ((t >= off) ? A[src][t - off] : 0);
        src ^= 1;
        __syncthreads();
    }
    if (t < nbl) histS[b * nbl + t] = (t > 0) ? A[src][t - 1] : 0;
    if (t == 0) tot[b] = A[src][nbl - 1];
}

__global__ __launch_bounds__(256) void k_scan_tot(const int* __restrict__ tot,
                                                  int* __restrict__ base) {
    __shared__ int A[2][NBUCKET];
    int t = threadIdx.x;
    A[0][t] = tot[t];
    __syncthreads();
    int src = 0;
    for (int off = 1; off < NBUCKET; off <<= 1) {
        A[1 - src][t] = A[src][t] + ((t >= off) ? A[src][t - off] : 0);
        src ^= 1;
        __syncthreads();
    }
    base[t] = (t > 0) ? A[src][t - 1] : 0;
    if (t == 255) base[NBUCKET] = A[src][255];
}

// 16384 edges per chunk, 1024 threads; LDS cursors; one 8B store per edge.
__global__ __launch_bounds__(1024) void k_scatter(const int* __restrict__ ei,
                                                  const float* __restrict__ ea,
                                                  const int* __restrict__ histS,
                                                  const int* __restrict__ base,
                                                  int2* __restrict__ binned,
                                                  int E, int E4, int nbl) {
    __shared__ int cur[NBUCKET];
    int t = threadIdx.x, bl = blockIdx.x;
    if (t < NBUCKET) cur[t] = base[t] + histS[t * nbl + bl];
    __syncthreads();
#pragma unroll
    for (int i = 0; i < 4; ++i) {
        int idx = bl * 4096 + i * 1024 + t;
        if (idx < E4) {
            int4   r = ((const int4*)ei)[idx];
            int4   c = ((const int4*)(ei + E))[idx];
            float4 w = ((const float4*)ea)[idx];
            int p;
            p = atomicAdd(&cur[c.x >> BSHIFT], 1);
            binned[p] = make_int2(((c.x & (BSIZE - 1)) << 17) | r.x, __float_as_int(w.x));
            p = atomicAdd(&cur[c.y >> BSHIFT], 1);
            binned[p] = make_int2(((c.y & (BSIZE - 1)) << 17) | r.y, __float_as_int(w.y));
            p = atomicAdd(&cur[c.z >> BSHIFT], 1);
            binned[p] = make_int2(((c.z & (BSIZE - 1)) << 17) | r.z, __float_as_int(w.z));
            p = atomicAdd(&cur[c.w >> BSHIFT], 1);
            binned[p] = make_int2(((c.w & (BSIZE - 1)) << 17) | r.w, __float_as_int(w.w));
        }
    }
}

// One block (1024 threads) per 512-node bucket: count + ew-sum + scan in LDS;
// emit offset, dinv, csr[p] = f16bits(ew)[14:0]<<17 | row.
__global__ __launch_bounds__(1024) void k_finalize(const int2* __restrict__ binned,
                                                   const int* __restrict__ base,
                                                   unsigned* __restrict__ csr,
                                                   int* __restrict__ offset,
                                                   float* __restrict__ dinv,
                                                   int N, int E) {
    __shared__ int   cnt[BSIZE];
    __shared__ float fsum[BSIZE];
    __shared__ int   inc[2][BSIZE];
    __shared__ int   cur[BSIZE];
    int b = blockIdx.x, t = threadIdx.x;
    int e0 = base[b], e1 = base[b + 1];
    for (int i = t; i < BSIZE; i += 1024) { cnt[i] = 0; fsum[i] = 0.f; }
    __syncthreads();
    for (int e = e0 + t; e < e1; e += 1024) {
        int2 ed = binned[e];
        unsigned cl = ((unsigned)ed.x) >> 17;
        atomicAdd(&cnt[cl], 1);
        atomicAdd(&fsum[cl], __int_as_float(ed.y));
    }
    __syncthreads();
    for (int i = t; i < BSIZE; i += 1024) inc[0][i] = cnt[i];
    __syncthreads();
    int src = 0;
    for (int off = 1; off < BSIZE; off <<= 1) {
        for (int i = t; i < BSIZE; i += 1024)
            inc[1 - src][i] = inc[src][i] + ((i >= off) ? inc[src][i - off] : 0);
        src ^= 1;
        __syncthreads();
    }
    int nodeBase = b << BSHIFT;
    for (int i = t; i < BSIZE; i += 1024) {
        int ex = (i > 0) ? inc[src][i - 1] : 0;
        cur[i] = e0 + ex;
        int node = nodeBase + i;
        if (node < N) {
            offset[node] = e0 + ex;
            dinv[node]   = rsqrtf(1.0f + fsum[i]);
        }
    }
    if (b == 0 && t == 0) offset[N] = E;
    __syncthreads();
    for (int e = e0 + t; e < e1; e += 1024) {
        int2 ed = binned[e];
        unsigned cl = ((unsigned)ed.x) >> 17;
        unsigned row = ((unsigned)ed.x) & 0x1FFFF;
        unsigned hb = (unsigned)__half_as_ushort(__float2half_rn(__int_as_float(ed.y))) & 0x7FFFu;
        int p = atomicAdd(&cur[cl], 1);
        csr[p] = (hb << 17) | row;
    }
}

// ---------------- dense compute (identical to R13) ----------------

__global__ __launch_bounds__(256) void k_gemm_mfma(const float* __restrict__ x,
                                                   const float* __restrict__ W1,
                                                   const float* __restrict__ dinv,
                                                   __half* __restrict__ hs, int n) {
    __shared__ _Float16 xh[64][136];
    __shared__ _Float16 wTh[64][136];
    int t = threadIdx.x;
    int nodeBase = blockIdx.x * 64;

    for (int i = t; i < 2048; i += 256) {
        int r = i >> 5, c4 = i & 31;
        int node = nodeBase + r;
        float4 v = make_float4(0.f, 0.f, 0.f, 0.f);
        if (node < n) v = ((const float4*)x)[node * 32 + c4];
        _Float16* dst = &xh[r][c4 * 4];
        dst[0] = (_Float16)v.x; dst[1] = (_Float16)v.y;
        dst[2] = (_Float16)v.z; dst[3] = (_Float16)v.w;
    }
    for (int i = t; i < 2048; i += 256) {
        int k = i >> 4, c4 = i & 15;
        float4 v = ((const float4*)W1)[k * 16 + c4];
        wTh[c4 * 4 + 0][k] = (_Float16)v.x;
        wTh[c4 * 4 + 1][k] = (_Float16)v.y;
        wTh[c4 * 4 + 2][k] = (_Float16)v.z;
        wTh[c4 * 4 + 3][k] = (_Float16)v.w;
    }
    __syncthreads();

    int w = t >> 6, lane = t & 63;
    int m = lane & 15, quad = lane >> 4;

    f32x4 acc[4] = {{0.f,0.f,0.f,0.f},{0.f,0.f,0.f,0.f},
                    {0.f,0.f,0.f,0.f},{0.f,0.f,0.f,0.f}};
#pragma unroll
    for (int ks = 0; ks < 128; ks += 32) {
        f16x8 a = *(const f16x8*)&xh[w * 16 + m][ks + quad * 8];
#pragma unroll
        for (int ct = 0; ct < 4; ++ct) {
            f16x8 bfr = *(const f16x8*)&wTh[ct * 16 + m][ks + quad * 8];
            acc[ct] = __builtin_amdgcn_mfma_f32_16x16x32_f16(a, bfr, acc[ct], 0, 0, 0);
        }
    }

#pragma unroll
    for (int reg = 0; reg < 4; ++reg) {
        int node = nodeBase + w * 16 + quad * 4 + reg;
        if (node < n) {
            float dv = dinv[node];
#pragma unroll
            for (int ct = 0; ct < 4; ++ct) {
                float v = acc[ct][reg] * dv;
                hs[(size_t)node * 64 + ct * 16 + m] = __float2half_rn(v);
            }
        }
    }
}

__global__ __launch_bounds__(256) void k_agg1(const __half* __restrict__ hs,
                                              const int* __restrict__ offset,
                                              const unsigned* __restrict__ csr,
                                              const float* __restrict__ dinv,
                                              const float* __restrict__ b1,
                                              const float* __restrict__ W2,
                                              float* __restrict__ h2s, int n) {
    int wid  = (int)((blockIdx.x * blockDim.x + threadIdx.x) >> 6);
    int lane = threadIdx.x & 63;
    if (wid >= n) return;
    int off0 = offset[wid], off1 = offset[wid + 1];
    int g = lane >> 3, s = lane & 7;
    const f16x8* H = (const f16x8*)hs;

    float acc[8] = {0.f, 0.f, 0.f, 0.f, 0.f, 0.f, 0.f, 0.f};

    {
        f16x8 v = H[(size_t)wid * 8 + s];
        if (g == 0) {
#pragma unroll
            for (int k = 0; k < 8; ++k) acc[k] += (float)v[k];
        }
    }

    for (int j = off0; j < off1; j += 32) {
        int   i0 = j + g,      i1 = j + 8 + g,  i2 = j + 16 + g, i3 = j + 24 + g;
        bool  k0 = i0 < off1,  k1 = i1 < off1,  k2 = i2 < off1,  k3 = i3 < off1;
        unsigned eA = csr[k0 ? i0 : off1 - 1];
        unsigned eB = csr[k1 ? i1 : off1 - 1];
        unsigned eC = csr[k2 ? i2 : off1 - 1];
        unsigned eD = csr[k3 ? i3 : off1 - 1];
        f16x8 vA = H[(size_t)(eA & 0x1FFFF) * 8 + s];
        f16x8 vB = H[(size_t)(eB & 0x1FFFF) * 8 + s];
        f16x8 vC = H[(size_t)(eC & 0x1FFFF) * 8 + s];
        f16x8 vD = H[(size_t)(eD & 0x1FFFF) * 8 + s];
        float wA = k0 ? (float)__ushort_as_half((unsigned short)(eA >> 17)) : 0.f;
        float wB = k1 ? (float)__ushort_as_half((unsigned short)(eB >> 17)) : 0.f;
        float wC = k2 ? (float)__ushort_as_half((unsigned short)(eC >> 17)) : 0.f;
        float wD = k3 ? (float)__ushort_as_half((unsigned short)(eD >> 17)) : 0.f;
#pragma unroll
        for (int k = 0; k < 8; ++k) {
            acc[k] += wA * (float)vA[k];
            acc[k] += wB * (float)vB[k];
            acc[k] += wC * (float)vC[k];
            acc[k] += wD * (float)vD[k];
        }
    }

#pragma unroll
    for (int k = 0; k < 8; ++k) {
        float tv = acc[k];
        tv += __shfl_xor(tv, 8);
        tv += __shfl_xor(tv, 16);
        tv += __shfl_xor(tv, 32);
        acc[k] = tv;
    }

    float di = dinv[wid];
    float4 bA = ((const float4*)b1)[s * 2], bB = ((const float4*)b1)[s * 2 + 1];
    float4 wA = ((const float4*)W2)[s * 2], wB = ((const float4*)W2)[s * 2 + 1];
    float p = 0.f;
    p += fmaxf(di * acc[0] + bA.x, 0.f) * wA.x;
    p += fmaxf(di * acc[1] + bA.y, 0.f) * wA.y;
    p += fmaxf(di * acc[2] + bA.z, 0.f) * wA.z;
    p += fmaxf(di * acc[3] + bA.w, 0.f) * wA.w;
    p += fmaxf(di * acc[4] + bB.x, 0.f) * wB.x;
    p += fmaxf(di * acc[5] + bB.y, 0.f) * wB.y;
    p += fmaxf(di * acc[6] + bB.z, 0.f) * wB.z;
    p += fmaxf(di * acc[7] + bB.w, 0.f) * wB.w;
    p += __shfl_xor(p, 1);
    p += __shfl_xor(p, 2);
    p += __shfl_xor(p, 4);
    if (lane == 0) h2s[wid] = di * p;
}

__global__ __launch_bounds__(256) void k_agg2(const float* __restrict__ h2s,
                                              const int* __restrict__ offset,
                                              const unsigned* __restrict__ csr,
                                              const float* __restrict__ dinv,
                                              const float* __restrict__ b2,
                                              float* __restrict__ out, int n) {
    int wid = __builtin_amdgcn_readfirstlane((int)((blockIdx.x * blockDim.x + threadIdx.x) >> 6));
    int lane = threadIdx.x & 63;
    if (wid >= n) return;
    int off0 = __builtin_amdgcn_readfirstlane(offset[wid]);
    int off1 = __builtin_amdgcn_readfirstlane(offset[wid + 1]);
    float di = dinv[wid];
    float p = 0.f;
    for (int e = off0 + lane; e < off1; e += 64) {
        unsigned ed = csr[e];
        p += (float)__ushort_as_half((unsigned short)(ed >> 17)) * h2s[ed & 0x1FFFF];
    }
#pragma unroll
    for (int s = 32; s > 0; s >>= 1) p += __shfl_xor(p, s);
    if (lane == 0) out[wid] = di * (p + h2s[wid]) + b2[0];
}

extern "C" void kernel_launch(void* const* d_in, const int* in_sizes, int n_in,
                              void* d_out, int out_size, void* d_ws, size_t ws_size,
                              hipStream_t stream) {
    const float* x  = (const float*)d_in[0];
    const int*   ei = (const int*)  d_in[1];
    const float* ea = (const float*)d_in[2];
    const float* W1 = (const float*)d_in[3];
    const float* b1 = (const float*)d_in[4];
    const float* W2 = (const float*)d_in[5];
    const float* b2 = (const float*)d_in[6];
    float* out = (float*)d_out;

    const int N  = in_sizes[0] / 128;   // 100000 (must be <= 131072)
    const int E  = in_sizes[2];         // 3200000
    const int E4 = E / 4;
    const int nbl  = (E4 + 4095) / 4096;        // 16384-edge chunks (196)
    const int nbkt = (N + BSIZE - 1) / BSIZE;   // active buckets (196)

    char* p = (char*)d_ws;
    auto alloc = [&](size_t bytes) -> void* {
        void* r = (void*)p;
        p += (bytes + 255) & ~(size_t)255;
        return r;
    };
    int*       hist   = (int*)      alloc((size_t)nbl * NBUCKET * 4);
    int*       histS  = (int*)      alloc((size_t)NBUCKET * nbl * 4);
    int*       tot    = (int*)      alloc((size_t)NBUCKET * 4);
    int*       base   = (int*)      alloc((size_t)(NBUCKET + 1) * 4);
    int2*      binned = (int2*)     alloc((size_t)E * 8);
    unsigned*  csr    = (unsigned*) alloc((size_t)E * 4);
    int*       offset = (int*)      alloc((size_t)(N + 1) * 4);
    float*     dinv   = (float*)    alloc((size_t)N * 4);
    __half*    hs     = (__half*)   alloc((size_t)N * 64 * 2);
    float*     h2s    = (float*)    alloc((size_t)N * 4);

    const int nb_gemm = (N + 63) / 64;
    const int nb_wave = (N * 64 + 255) / 256;   // one 64-wide wave per node

    k_hist<<<nbl, 1024, 0, stream>>>(ei + E, hist, E4);
    k_scan_bucket<<<NBUCKET, 256, 0, stream>>>(hist, histS, tot, nbl);
    k_scan_tot<<<1, 256, 0, stream>>>(tot, base);
    k_scatter<<<nbl, 1024, 0, stream>>>(ei, ea, histS, base, binned, E, E4, nbl);
    k_finalize<<<nbkt, 1024, 0, stream>>>(binned, base, csr, offset, dinv, N, E);
    k_gemm_mfma<<<nb_gemm, 256, 0, stream>>>(x, W1, dinv, hs, N);
    k_agg1<<<nb_wave, 256, 0, stream>>>(hs, offset, csr, dinv, b1, W2, h2s, N);
    k_agg2<<<nb_wave, 256, 0, stream>>>(h2s, offset, csr, dinv, b2, out, N);
}